// Round 3
// baseline (366.285 us; speedup 1.0000x reference)
//
#include <hip/hip_runtime.h>
#include <hip/hip_bf16.h>

// Problem geometry (fixed by setup_inputs)
#define BATCH 4
#define DZ 96
#define DY 192
#define DX 192
#define ZS (DY * DX)            // 36864
#define SVOL ((size_t)DZ * ZS)  // 3538944 voxels per batch item
#define NTOT ((double)(BATCH * (double)SVOL))
#define VOX_PER_THREAD 8
#define BLOCK 256
#define BLOCKS_PER_BATCH ((int)(SVOL / (VOX_PER_THREAD * BLOCK))) // 1728
#define GRID (BATCH * BLOCKS_PER_BATCH)                           // 6912

#define WORDS_TOTAL ((int)((BATCH * SVOL) / 64))   // 221184 u64 words
#define MAP_BYTES ((size_t)WORDS_TOTAL * 8)        // 1769472 B per bitmap
#define WS_HDR 128                                 // S1,S2,cnt header
#define WS_NEED (WS_HDR + 3 * MAP_BYTES)

// Exact expanding-box search for voxels whose entire 26-neighborhood matches
// their own class (expected ~0.2 such voxels in the whole 14M-voxel tensor).
__device__ __noinline__ int far_dist(const int* __restrict__ T, size_t bOff,
                                     int z, int y, int x, int tv) {
    for (int r = 2; r <= 20; ++r) {
        int zlo = max(z - r, 0), zhi = min(z + r, DZ - 1);
        int ylo = max(y - r, 0), yhi = min(y + r, DY - 1);
        int xlo = max(x - r, 0), xhi = min(x + r, DX - 1);
        for (int zz = zlo; zz <= zhi; ++zz)
            for (int yy = ylo; yy <= yhi; ++yy) {
                const int* rp = T + bOff + (size_t)zz * ZS + (size_t)yy * DX;
                for (int xx = xlo; xx <= xhi; ++xx)
                    if (rp[xx] != tv) return r;
            }
    }
    return 21;
}

// ---------------- pack kernel: int32 targets -> 3 bitmaps + init accum ------
__global__ __launch_bounds__(256) void pack_kernel(
    const int* __restrict__ tgt,
    unsigned long long* __restrict__ Tm,
    unsigned long long* __restrict__ Om,
    unsigned long long* __restrict__ Am,
    double* __restrict__ S1, double* __restrict__ S2, int* __restrict__ cnt)
{
    const int tid = blockIdx.x * 256 + threadIdx.x;
    if (blockIdx.x == 0 && threadIdx.x == 0) {
        #pragma unroll
        for (int i = 0; i < BATCH; ++i) { S1[i] = 0.0; S2[i] = 0.0; cnt[i] = 0; }
    }
    const int t = tgt[tid];
    const unsigned long long b = __ballot(t != 0);
    const int w = tid >> 6;                       // u64 word index
    const int lane = threadIdx.x & 63;
    const int xw = (w % 3) * 64;                  // word position in its 192-row
    const size_t base = ((size_t)w) << 6;

    int ev = 0;                                   // edge voxel value (lanes 0,63)
    if (lane == 0 && xw != 0)    ev = tgt[base - 1];
    if (lane == 63 && xw != 128) ev = tgt[base + 64];
    const int eL0 = __shfl(ev, 0);
    const int eR0 = __shfl(ev, 63);

    const unsigned long long eLor  = (xw != 0   && eL0 != 0) ? 1ull : 0ull;
    const unsigned long long eRor  = (xw != 128 && eR0 != 0) ? (1ull << 63) : 0ull;
    const unsigned long long eLand = (xw == 0   || eL0 != 0) ? 1ull : 0ull;
    const unsigned long long eRand = (xw == 128 || eR0 != 0) ? (1ull << 63) : 0ull;

    const unsigned long long horOR  = b | (b << 1) | (b >> 1) | eLor | eRor;
    const unsigned long long horAND = b & ((b << 1) | eLand) & ((b >> 1) | eRand);

    if (lane == 0) { Tm[w] = b; Om[w] = horOR; Am[w] = horAND; }
}

// ---------------- main kernel ----------------------------------------------
__global__ __launch_bounds__(BLOCK) void boundary_loss_kernel(
    const float* __restrict__ inp,
    const int* __restrict__ tgt,
    const unsigned long long* __restrict__ Tm,
    const unsigned long long* __restrict__ Om,
    const unsigned long long* __restrict__ Am,
    double* __restrict__ S1, double* __restrict__ S2, int* __restrict__ cnt)
{
    const int b = blockIdx.x / BLOCKS_PER_BATCH;
    const size_t bOff = (size_t)b * SVOL;
    const int gid = blockIdx.x * BLOCK + threadIdx.x;
    const size_t vox = (size_t)gid * VOX_PER_THREAD;
    const int rem = (int)(vox - bOff);
    const int z = rem / ZS;
    const int ry = rem - z * ZS;
    const int y = ry / DX;
    const int x0 = ry - y * DX;

    const size_t rowC = (size_t)(b * DZ + z) * DY + y;   // global row index
    const int bx = x0 >> 3;
    const unsigned char* O8 = (const unsigned char*)Om;
    const unsigned char* A8 = (const unsigned char*)Am;
    const unsigned char* T8 = (const unsigned char*)Tm;

    const int dzo[3] = {(z > 0) ? -1 : 0, 0, (z < DZ - 1) ? 1 : 0};
    const int vzf[3] = {z > 0, 1, z < DZ - 1};
    const int dyo[3] = {(y > 0) ? -1 : 0, 0, (y < DY - 1) ? 1 : 0};
    const int vyf[3] = {y > 0, 1, y < DY - 1};

    unsigned int or9 = 0u, and9 = 0xFFu;
    #pragma unroll
    for (int iz = 0; iz < 3; ++iz) {
        #pragma unroll
        for (int iy = 0; iy < 3; ++iy) {
            const size_t ba = (rowC + (long)dzo[iz] * DY + dyo[iy]) * 24 + bx;
            const unsigned int o = O8[ba];
            const unsigned int a = A8[ba];
            const unsigned int m = (vzf[iz] & vyf[iy]) ? 0xFFu : 0u;
            or9  |= o & m;
            and9 &= a | ~m;
        }
    }
    and9 &= 0xFFu;
    const unsigned int diff8 = or9 ^ and9;       // bit i: voxel has opposite 26-neighbor
    const unsigned int tc8 = T8[rowC * 24 + bx]; // bit i: t at voxel x0+i

    // probs_fg = sigmoid(x1 - x0)
    const size_t sp = (size_t)z * ZS + (size_t)y * DX + x0;
    const float* i0 = inp + ((size_t)(2 * b)) * SVOL + sp;
    const float* i1 = i0 + SVOL;
    float4 A0 = *(const float4*)(i0), A1 = *(const float4*)(i0 + 4);
    float4 B0 = *(const float4*)(i1), B1 = *(const float4*)(i1 + 4);
    float c0[8] = {A0.x, A0.y, A0.z, A0.w, A1.x, A1.y, A1.z, A1.w};
    float c1[8] = {B0.x, B0.y, B0.z, B0.w, B1.x, B1.y, B1.z, B1.w};

    float s1 = 0.f, s2 = 0.f;
    #pragma unroll
    for (int i = 0; i < VOX_PER_THREAD; ++i) {
        float e   = __expf(c0[i] - c1[i]);
        float sig = __builtin_amdgcn_rcpf(1.0f + e);
        int ti = (int)((tc8 >> i) & 1u);
        float val = (float)ti;                   // D==1 closed form
        if (!((diff8 >> i) & 1u)) {              // astronomically rare
            int D = far_dist(tgt, bOff, z, y, x0 + i, ti);
            int mm = min(D - 1, 20);
            val = ti ? (1.0f - (float)mm) : (float)mm;
        }
        s1 = fmaf(sig, val, s1);
        s2 += sig;
    }

    int ba_fg = __syncthreads_or((int)(tc8 != 0u));

    #pragma unroll
    for (int off = 32; off > 0; off >>= 1) {
        s1 += __shfl_down(s1, off);
        s2 += __shfl_down(s2, off);
    }
    __shared__ float red1[BLOCK / 64], red2[BLOCK / 64];
    const int lane = threadIdx.x & 63, wid = threadIdx.x >> 6;
    if (lane == 0) { red1[wid] = s1; red2[wid] = s2; }
    __syncthreads();
    if (threadIdx.x == 0) {
        atomicAdd(&S1[b], (double)(red1[0] + red1[1] + red1[2] + red1[3]));
        atomicAdd(&S2[b], (double)(red2[0] + red2[1] + red2[2] + red2[3]));
        if (ba_fg) atomicOr(&cnt[b], 1);
    }
}

// ---------------- fallback (R2 kernel, used only if ws too small) -----------
__global__ void initws_kernel(double* S1, double* S2, int* cnt) {
    for (int i = 0; i < BATCH; ++i) { S1[i] = 0.0; S2[i] = 0.0; cnt[i] = 0; }
}

__global__ __launch_bounds__(BLOCK) void boundary_loss_fallback(
    const float* __restrict__ inp, const int* __restrict__ tgt,
    double* __restrict__ S1, double* __restrict__ S2, int* __restrict__ cnt)
{
    const int b = blockIdx.x / BLOCKS_PER_BATCH;
    const size_t bOff = (size_t)b * SVOL;
    const int gid = blockIdx.x * BLOCK + threadIdx.x;
    const size_t vox = (size_t)gid * VOX_PER_THREAD;
    const int rem = (int)(vox - bOff);
    const int z = rem / ZS;
    const int ry = rem - z * ZS;
    const int y = ry / DX;
    const int x0 = ry - y * DX;

    uint32_t mxo = ~0u, mxa = 0u;
    if (x0 == 0)      { mxo &= ~1u;        mxa |= 1u; }
    if (x0 == DX - 8) { mxo &= ~(1u << 9); mxa |= (1u << 9); }
    const int ax = (x0 == 0) ? 0 : x0 - 4;
    const int dx8 = (x0 == DX - 8) ? DX - 1 : x0 + 8;

    uint32_t OR9 = 0u, AND9 = ~0u, pc = 0u;
    const int* Tb = tgt + bOff;
    #pragma unroll
    for (int dz = -1; dz <= 1; ++dz) {
        int zz = z + dz;
        if (zz < 0 || zz >= DZ) continue;
        #pragma unroll
        for (int dy = -1; dy <= 1; ++dy) {
            int yy = y + dy;
            if (yy < 0 || yy >= DY) continue;
            const int* rp = Tb + (size_t)zz * ZS + (size_t)yy * DX;
            int4 a = *(const int4*)(rp + ax);
            int4 q = *(const int4*)(rp + x0);
            int4 c = *(const int4*)(rp + x0 + 4);
            int  dd = rp[dx8];
            uint32_t p = (uint32_t)a.w
                | ((uint32_t)q.x << 1) | ((uint32_t)q.y << 2)
                | ((uint32_t)q.z << 3) | ((uint32_t)q.w << 4)
                | ((uint32_t)c.x << 5) | ((uint32_t)c.y << 6)
                | ((uint32_t)c.z << 7) | ((uint32_t)c.w << 8)
                | ((uint32_t)dd  << 9);
            if (dz == 0 && dy == 0) pc = p;
            uint32_t po = p & mxo;
            uint32_t pa = p | mxa;
            OR9  |= po | (po >> 1) | (po >> 2);
            AND9 &= pa & (pa >> 1) & (pa >> 2);
        }
    }
    const uint32_t diff8 = (OR9 ^ AND9) & 0xFFu;
    const uint32_t tc8   = (pc >> 1) & 0xFFu;

    const size_t sp = (size_t)z * ZS + (size_t)y * DX + x0;
    const float* i0 = inp + ((size_t)(2 * b)) * SVOL + sp;
    const float* i1 = i0 + SVOL;
    float4 A0 = *(const float4*)(i0), A1 = *(const float4*)(i0 + 4);
    float4 B0 = *(const float4*)(i1), B1 = *(const float4*)(i1 + 4);
    float c0[8] = {A0.x, A0.y, A0.z, A0.w, A1.x, A1.y, A1.z, A1.w};
    float c1[8] = {B0.x, B0.y, B0.z, B0.w, B1.x, B1.y, B1.z, B1.w};

    float s1 = 0.f, s2 = 0.f;
    #pragma unroll
    for (int i = 0; i < VOX_PER_THREAD; ++i) {
        float e   = __expf(c0[i] - c1[i]);
        float sig = __builtin_amdgcn_rcpf(1.0f + e);
        int ti = (int)((tc8 >> i) & 1u);
        float val = (float)ti;
        if (!((diff8 >> i) & 1u)) {
            int D = far_dist(tgt, bOff, z, y, x0 + i, ti);
            int mm = min(D - 1, 20);
            val = ti ? (1.0f - (float)mm) : (float)mm;
        }
        s1 = fmaf(sig, val, s1);
        s2 += sig;
    }

    int ba_fg = __syncthreads_or((int)(tc8 != 0u));
    #pragma unroll
    for (int off = 32; off > 0; off >>= 1) {
        s1 += __shfl_down(s1, off);
        s2 += __shfl_down(s2, off);
    }
    __shared__ float red1[BLOCK / 64], red2[BLOCK / 64];
    const int lane = threadIdx.x & 63, wid = threadIdx.x >> 6;
    if (lane == 0) { red1[wid] = s1; red2[wid] = s2; }
    __syncthreads();
    if (threadIdx.x == 0) {
        atomicAdd(&S1[b], (double)(red1[0] + red1[1] + red1[2] + red1[3]));
        atomicAdd(&S2[b], (double)(red2[0] + red2[1] + red2[2] + red2[3]));
        if (ba_fg) atomicOr(&cnt[b], 1);
    }
}

__global__ void finalize_kernel(const double* __restrict__ S1,
                                const double* __restrict__ S2,
                                const int* __restrict__ cnt,
                                float* __restrict__ out) {
    double tot = 0.0;
    for (int b = 0; b < BATCH; ++b)
        tot += cnt[b] ? S1[b] : S2[b];
    out[0] = (float)(tot / NTOT);
}

extern "C" void kernel_launch(void* const* d_in, const int* in_sizes, int n_in,
                              void* d_out, int out_size, void* d_ws, size_t ws_size,
                              hipStream_t stream) {
    const float* inp = (const float*)d_in[0];
    const int*   tgt = (const int*)d_in[1];
    float* out = (float*)d_out;

    double* S1 = (double*)d_ws;
    double* S2 = S1 + BATCH;
    int*   cnt = (int*)(S2 + BATCH);

    if (ws_size >= WS_NEED) {
        unsigned long long* Tm = (unsigned long long*)((char*)d_ws + WS_HDR);
        unsigned long long* Om = Tm + WORDS_TOTAL;
        unsigned long long* Am = Om + WORDS_TOTAL;
        hipLaunchKernelGGL(pack_kernel, dim3((BATCH * (int)SVOL) / 256), dim3(256),
                           0, stream, tgt, Tm, Om, Am, S1, S2, cnt);
        hipLaunchKernelGGL(boundary_loss_kernel, dim3(GRID), dim3(BLOCK), 0, stream,
                           inp, tgt, Tm, Om, Am, S1, S2, cnt);
    } else {
        hipLaunchKernelGGL(initws_kernel, dim3(1), dim3(1), 0, stream, S1, S2, cnt);
        hipLaunchKernelGGL(boundary_loss_fallback, dim3(GRID), dim3(BLOCK), 0, stream,
                           inp, tgt, S1, S2, cnt);
    }
    hipLaunchKernelGGL(finalize_kernel, dim3(1), dim3(1), 0, stream, S1, S2, cnt, out);
}

// Round 4
// 240.413 us; speedup vs baseline: 1.5236x; 1.5236x over previous
//
#include <hip/hip_runtime.h>
#include <hip/hip_bf16.h>

// Problem geometry (fixed by setup_inputs)
#define BATCH 4
#define DZ 96
#define DY 192
#define DX 192
#define ZS (DY * DX)            // 36864
#define SVOL ((size_t)DZ * ZS)  // 3538944 voxels per batch item
#define NTOT ((double)(BATCH * (double)SVOL))
#define VOX_PER_THREAD 8
#define BLOCK 256
#define BLOCKS_PER_BATCH ((int)(SVOL / (VOX_PER_THREAD * BLOCK))) // 1728
#define GRID (BATCH * BLOCKS_PER_BATCH)                           // 6912

#define WORDS_TOTAL ((int)((BATCH * SVOL) / 64))   // 221184 u64 words
#define MAP_BYTES ((size_t)WORDS_TOTAL * 8)        // 1769472 B per bitmap
#define PART_BYTES ((size_t)GRID * 16)             // float4 per block
#define WS_NEED (PART_BYTES + 3 * MAP_BYTES)

// Exact expanding-box search for voxels whose entire 26-neighborhood matches
// their own class (expected ~10 such voxels in the whole 14M-voxel tensor,
// nearly all at faces/edges where the neighborhood is truncated).
__device__ __noinline__ int far_dist(const int* __restrict__ T, size_t bOff,
                                     int z, int y, int x, int tv) {
    for (int r = 2; r <= 20; ++r) {
        int zlo = max(z - r, 0), zhi = min(z + r, DZ - 1);
        int ylo = max(y - r, 0), yhi = min(y + r, DY - 1);
        int xlo = max(x - r, 0), xhi = min(x + r, DX - 1);
        for (int zz = zlo; zz <= zhi; ++zz)
            for (int yy = ylo; yy <= yhi; ++yy) {
                const int* rp = T + bOff + (size_t)zz * ZS + (size_t)yy * DX;
                for (int xx = xlo; xx <= xhi; ++xx)
                    if (rp[xx] != tv) return r;
            }
    }
    return 21;
}

// ---------------- pack kernel: int32 targets -> 3 bitmaps -------------------
__global__ __launch_bounds__(256) void pack_kernel(
    const int* __restrict__ tgt,
    unsigned long long* __restrict__ Tm,
    unsigned long long* __restrict__ Om,
    unsigned long long* __restrict__ Am)
{
    const int tid = blockIdx.x * 256 + threadIdx.x;
    const int t = tgt[tid];
    const unsigned long long b = __ballot(t != 0);
    const int w = tid >> 6;                       // u64 word index
    const int lane = threadIdx.x & 63;
    const int xw = (w % 3) * 64;                  // word position in its 192-row
    const size_t base = ((size_t)w) << 6;

    int ev = 0;                                   // edge voxel value (lanes 0,63)
    if (lane == 0 && xw != 0)    ev = tgt[base - 1];
    if (lane == 63 && xw != 128) ev = tgt[base + 64];
    const int eL0 = __shfl(ev, 0);
    const int eR0 = __shfl(ev, 63);

    const unsigned long long eLor  = (xw != 0   && eL0 != 0) ? 1ull : 0ull;
    const unsigned long long eRor  = (xw != 128 && eR0 != 0) ? (1ull << 63) : 0ull;
    const unsigned long long eLand = (xw == 0   || eL0 != 0) ? 1ull : 0ull;
    const unsigned long long eRand = (xw == 128 || eR0 != 0) ? (1ull << 63) : 0ull;

    const unsigned long long horOR  = b | (b << 1) | (b >> 1) | eLor | eRor;
    const unsigned long long horAND = b & ((b << 1) | eLand) & ((b >> 1) | eRand);

    if (lane == 0) { Tm[w] = b; Om[w] = horOR; Am[w] = horAND; }
}

// ---------------- main kernel: per-block partials, NO contended atomics -----
__global__ __launch_bounds__(BLOCK) void boundary_loss_kernel(
    const float* __restrict__ inp,
    const int* __restrict__ tgt,
    const unsigned long long* __restrict__ Om,
    const unsigned long long* __restrict__ Am,
    const unsigned long long* __restrict__ Tm,
    float4* __restrict__ P)          // per-block (s1, s2, fg, 0)
{
    const int b = blockIdx.x / BLOCKS_PER_BATCH;
    const size_t bOff = (size_t)b * SVOL;
    const int gid = blockIdx.x * BLOCK + threadIdx.x;
    const size_t vox = (size_t)gid * VOX_PER_THREAD;
    const int rem = (int)(vox - bOff);
    const int z = rem / ZS;
    const int ry = rem - z * ZS;
    const int y = ry / DX;
    const int x0 = ry - y * DX;

    const size_t rowC = (size_t)(b * DZ + z) * DY + y;   // global row index
    const int bx = x0 >> 3;
    const unsigned char* O8 = (const unsigned char*)Om;
    const unsigned char* A8 = (const unsigned char*)Am;
    const unsigned char* T8 = (const unsigned char*)Tm;

    const int dzo[3] = {(z > 0) ? -1 : 0, 0, (z < DZ - 1) ? 1 : 0};
    const int vzf[3] = {z > 0, 1, z < DZ - 1};
    const int dyo[3] = {(y > 0) ? -1 : 0, 0, (y < DY - 1) ? 1 : 0};
    const int vyf[3] = {y > 0, 1, y < DY - 1};

    unsigned int or9 = 0u, and9 = 0xFFu;
    #pragma unroll
    for (int iz = 0; iz < 3; ++iz) {
        #pragma unroll
        for (int iy = 0; iy < 3; ++iy) {
            const size_t ba = (rowC + (long)dzo[iz] * DY + dyo[iy]) * 24 + bx;
            const unsigned int o = O8[ba];
            const unsigned int a = A8[ba];
            const unsigned int m = (vzf[iz] & vyf[iy]) ? 0xFFu : 0u;
            or9  |= o & m;
            and9 &= a | ~m;
        }
    }
    and9 &= 0xFFu;
    const unsigned int diff8 = or9 ^ and9;       // bit i: voxel has opposite 26-neighbor
    const unsigned int tc8 = T8[rowC * 24 + bx]; // bit i: t at voxel x0+i

    // probs_fg = sigmoid(x1 - x0)
    const size_t sp = (size_t)z * ZS + (size_t)y * DX + x0;
    const float* i0 = inp + ((size_t)(2 * b)) * SVOL + sp;
    const float* i1 = i0 + SVOL;
    float4 A0 = *(const float4*)(i0), A1 = *(const float4*)(i0 + 4);
    float4 B0 = *(const float4*)(i1), B1 = *(const float4*)(i1 + 4);
    float c0[8] = {A0.x, A0.y, A0.z, A0.w, A1.x, A1.y, A1.z, A1.w};
    float c1[8] = {B0.x, B0.y, B0.z, B0.w, B1.x, B1.y, B1.z, B1.w};

    float s1 = 0.f, s2 = 0.f;
    #pragma unroll
    for (int i = 0; i < VOX_PER_THREAD; ++i) {
        float e   = __expf(c0[i] - c1[i]);
        float sig = __builtin_amdgcn_rcpf(1.0f + e);
        int ti = (int)((tc8 >> i) & 1u);
        float val = (float)ti;                   // D==1 closed form
        if (!((diff8 >> i) & 1u)) {              // astronomically rare
            int D = far_dist(tgt, bOff, z, y, x0 + i, ti);
            int mm = min(D - 1, 20);
            val = ti ? (1.0f - (float)mm) : (float)mm;
        }
        s1 = fmaf(sig, val, s1);
        s2 += sig;
    }
    float s3 = (tc8 != 0u) ? 1.f : 0.f;          // foreground presence

    // wave reduce (64 lanes), then block reduce via LDS, single plain store
    #pragma unroll
    for (int off = 32; off > 0; off >>= 1) {
        s1 += __shfl_down(s1, off);
        s2 += __shfl_down(s2, off);
        s3 += __shfl_down(s3, off);
    }
    __shared__ float red1[BLOCK / 64], red2[BLOCK / 64], red3[BLOCK / 64];
    const int lane = threadIdx.x & 63, wid = threadIdx.x >> 6;
    if (lane == 0) { red1[wid] = s1; red2[wid] = s2; red3[wid] = s3; }
    __syncthreads();
    if (threadIdx.x == 0) {
        float b1 = red1[0] + red1[1] + red1[2] + red1[3];
        float b2 = red2[0] + red2[1] + red2[2] + red2[3];
        float b3 = red3[0] + red3[1] + red3[2] + red3[3];
        P[blockIdx.x] = make_float4(b1, b2, b3, 0.f);
    }
}

// ---------------- direct fallback (only if ws too small for bitmaps) --------
__global__ __launch_bounds__(BLOCK) void boundary_loss_fallback(
    const float* __restrict__ inp, const int* __restrict__ tgt,
    float4* __restrict__ P)
{
    const int b = blockIdx.x / BLOCKS_PER_BATCH;
    const size_t bOff = (size_t)b * SVOL;
    const int gid = blockIdx.x * BLOCK + threadIdx.x;
    const size_t vox = (size_t)gid * VOX_PER_THREAD;
    const int rem = (int)(vox - bOff);
    const int z = rem / ZS;
    const int ry = rem - z * ZS;
    const int y = ry / DX;
    const int x0 = ry - y * DX;

    uint32_t mxo = ~0u, mxa = 0u;
    if (x0 == 0)      { mxo &= ~1u;        mxa |= 1u; }
    if (x0 == DX - 8) { mxo &= ~(1u << 9); mxa |= (1u << 9); }
    const int ax = (x0 == 0) ? 0 : x0 - 4;
    const int dx8 = (x0 == DX - 8) ? DX - 1 : x0 + 8;

    uint32_t OR9 = 0u, AND9 = ~0u, pc = 0u;
    const int* Tb = tgt + bOff;
    #pragma unroll
    for (int dz = -1; dz <= 1; ++dz) {
        int zz = z + dz;
        if (zz < 0 || zz >= DZ) continue;
        #pragma unroll
        for (int dy = -1; dy <= 1; ++dy) {
            int yy = y + dy;
            if (yy < 0 || yy >= DY) continue;
            const int* rp = Tb + (size_t)zz * ZS + (size_t)yy * DX;
            int4 a = *(const int4*)(rp + ax);
            int4 q = *(const int4*)(rp + x0);
            int4 c = *(const int4*)(rp + x0 + 4);
            int  dd = rp[dx8];
            uint32_t p = (uint32_t)a.w
                | ((uint32_t)q.x << 1) | ((uint32_t)q.y << 2)
                | ((uint32_t)q.z << 3) | ((uint32_t)q.w << 4)
                | ((uint32_t)c.x << 5) | ((uint32_t)c.y << 6)
                | ((uint32_t)c.z << 7) | ((uint32_t)c.w << 8)
                | ((uint32_t)dd  << 9);
            if (dz == 0 && dy == 0) pc = p;
            uint32_t po = p & mxo;
            uint32_t pa = p | mxa;
            OR9  |= po | (po >> 1) | (po >> 2);
            AND9 &= pa & (pa >> 1) & (pa >> 2);
        }
    }
    const uint32_t diff8 = (OR9 ^ AND9) & 0xFFu;
    const uint32_t tc8   = (pc >> 1) & 0xFFu;

    const size_t sp = (size_t)z * ZS + (size_t)y * DX + x0;
    const float* i0 = inp + ((size_t)(2 * b)) * SVOL + sp;
    const float* i1 = i0 + SVOL;
    float4 A0 = *(const float4*)(i0), A1 = *(const float4*)(i0 + 4);
    float4 B0 = *(const float4*)(i1), B1 = *(const float4*)(i1 + 4);
    float c0[8] = {A0.x, A0.y, A0.z, A0.w, A1.x, A1.y, A1.z, A1.w};
    float c1[8] = {B0.x, B0.y, B0.z, B0.w, B1.x, B1.y, B1.z, B1.w};

    float s1 = 0.f, s2 = 0.f;
    #pragma unroll
    for (int i = 0; i < VOX_PER_THREAD; ++i) {
        float e   = __expf(c0[i] - c1[i]);
        float sig = __builtin_amdgcn_rcpf(1.0f + e);
        int ti = (int)((tc8 >> i) & 1u);
        float val = (float)ti;
        if (!((diff8 >> i) & 1u)) {
            int D = far_dist(tgt, bOff, z, y, x0 + i, ti);
            int mm = min(D - 1, 20);
            val = ti ? (1.0f - (float)mm) : (float)mm;
        }
        s1 = fmaf(sig, val, s1);
        s2 += sig;
    }
    float s3 = (tc8 != 0u) ? 1.f : 0.f;

    #pragma unroll
    for (int off = 32; off > 0; off >>= 1) {
        s1 += __shfl_down(s1, off);
        s2 += __shfl_down(s2, off);
        s3 += __shfl_down(s3, off);
    }
    __shared__ float red1[BLOCK / 64], red2[BLOCK / 64], red3[BLOCK / 64];
    const int lane = threadIdx.x & 63, wid = threadIdx.x >> 6;
    if (lane == 0) { red1[wid] = s1; red2[wid] = s2; red3[wid] = s3; }
    __syncthreads();
    if (threadIdx.x == 0) {
        P[blockIdx.x] = make_float4(red1[0] + red1[1] + red1[2] + red1[3],
                                    red2[0] + red2[1] + red2[2] + red2[3],
                                    red3[0] + red3[1] + red3[2] + red3[3], 0.f);
    }
}

// ---------------- final reduction: 6912 partials -> scalar loss -------------
__global__ __launch_bounds__(1024) void reduce_kernel(
    const float4* __restrict__ P, float* __restrict__ out)
{
    const int tid = threadIdx.x;
    const int lane = tid & 63, wid = tid >> 6;
    __shared__ double L1[16], L2[16], L3[16];
    double tot = 0.0;

    for (int b = 0; b < BATCH; ++b) {
        double d1 = 0.0, d2 = 0.0, d3 = 0.0;
        for (int i = tid; i < BLOCKS_PER_BATCH; i += 1024) {
            float4 p = P[b * BLOCKS_PER_BATCH + i];
            d1 += p.x; d2 += p.y; d3 += p.z;
        }
        #pragma unroll
        for (int off = 32; off > 0; off >>= 1) {
            d1 += __shfl_down(d1, off);
            d2 += __shfl_down(d2, off);
            d3 += __shfl_down(d3, off);
        }
        if (lane == 0) { L1[wid] = d1; L2[wid] = d2; L3[wid] = d3; }
        __syncthreads();
        if (tid == 0) {
            double s1 = 0.0, s2 = 0.0, s3 = 0.0;
            #pragma unroll
            for (int w = 0; w < 16; ++w) { s1 += L1[w]; s2 += L2[w]; s3 += L3[w]; }
            tot += (s3 > 0.0) ? s1 : s2;   // no_fg batch: dist_map == 1 everywhere
        }
        __syncthreads();
    }
    if (tid == 0) out[0] = (float)(tot / NTOT);
}

extern "C" void kernel_launch(void* const* d_in, const int* in_sizes, int n_in,
                              void* d_out, int out_size, void* d_ws, size_t ws_size,
                              hipStream_t stream) {
    const float* inp = (const float*)d_in[0];
    const int*   tgt = (const int*)d_in[1];
    float* out = (float*)d_out;

    float4* P = (float4*)d_ws;                    // 6912 * 16 B
    if (ws_size >= WS_NEED) {
        unsigned long long* Tm = (unsigned long long*)((char*)d_ws + PART_BYTES);
        unsigned long long* Om = Tm + WORDS_TOTAL;
        unsigned long long* Am = Om + WORDS_TOTAL;
        hipLaunchKernelGGL(pack_kernel, dim3((BATCH * (int)SVOL) / 256), dim3(256),
                           0, stream, tgt, Tm, Om, Am);
        hipLaunchKernelGGL(boundary_loss_kernel, dim3(GRID), dim3(BLOCK), 0, stream,
                           inp, tgt, Om, Am, Tm, P);
    } else {
        hipLaunchKernelGGL(boundary_loss_fallback, dim3(GRID), dim3(BLOCK), 0, stream,
                           inp, tgt, P);
    }
    hipLaunchKernelGGL(reduce_kernel, dim3(1), dim3(1024), 0, stream, P, out);
}